// Round 1
// baseline (137.103 us; speedup 1.0000x reference)
//
#include <hip/hip_runtime.h>
#include <math.h>

#define B_ 4
#define L_ 4096
#define D_ 512
#define HD_ 64
#define VD_ 128
#define C_ 64
#define NC_ (L_/C_)      // 64 chunks per batch
#define GAMMA_ 0.96875f

// -------------------------------------------------------------------------
// K1: fused projection (X @ W) + xPos epilogue.
// grid (M/64, 4): blockIdx.y selects {Q, K, V-lo, V-hi}. 256 threads, 4x4 micro-tile.
// -------------------------------------------------------------------------
__global__ __launch_bounds__(256) void k_proj(
    const float* __restrict__ X, const float* __restrict__ WQ,
    const float* __restrict__ WK, const float* __restrict__ WV,
    float* __restrict__ Qf, float* __restrict__ Kf, float* __restrict__ Vf)
{
    const int bm = blockIdx.x;
    const int ct = blockIdx.y;
    const float* W; float* Out; int ldw, colOff, xposMode;
    if (ct == 0)      { W = WQ; Out = Qf; ldw = 64;  colOff = 0;  xposMode = 1; }
    else if (ct == 1) { W = WK; Out = Kf; ldw = 64;  colOff = 0;  xposMode = 2; }
    else              { W = WV; Out = Vf; ldw = 128; colOff = (ct-2)*64; xposMode = 0; }

    __shared__ float As[32][64];   // As[k][m]  (X tile, transposed on store)
    __shared__ float Bs[32][64];   // Bs[k][n]  (W tile)

    const int tid = threadIdx.x;
    const int tx = tid & 15, ty = tid >> 4;
    const int row0 = bm * 64;
    float acc[4][4] = {};

    for (int k0 = 0; k0 < D_; k0 += 32) {
        #pragma unroll
        for (int it = 0; it < 2; ++it) {
            int idx = tid + it*256;                 // 0..511
            int m = idx >> 3, kk = (idx & 7) << 2;
            float4 v = *(const float4*)&X[(size_t)(row0+m)*D_ + k0 + kk];
            As[kk+0][m] = v.x; As[kk+1][m] = v.y; As[kk+2][m] = v.z; As[kk+3][m] = v.w;
        }
        #pragma unroll
        for (int it = 0; it < 2; ++it) {
            int idx = tid + it*256;                 // 0..511
            int kk = idx >> 4, n = (idx & 15) << 2;
            *(float4*)&Bs[kk][n] = *(const float4*)&W[(size_t)(k0+kk)*ldw + colOff + n];
        }
        __syncthreads();
        #pragma unroll
        for (int k = 0; k < 32; ++k) {
            float4 a = *(const float4*)&As[k][ty<<2];
            float4 b = *(const float4*)&Bs[k][tx<<2];
            float av[4] = {a.x,a.y,a.z,a.w};
            float bv[4] = {b.x,b.y,b.z,b.w};
            #pragma unroll
            for (int i = 0; i < 4; ++i)
                #pragma unroll
                for (int j = 0; j < 4; ++j)
                    acc[i][j] = fmaf(av[i], bv[j], acc[i][j]);
        }
        __syncthreads();
    }

    const int c0 = tx << 2;     // 4 consecutive output cols -> rotary pairs local
    #pragma unroll
    for (int i = 0; i < 4; ++i) {
        int row = row0 + (ty<<2) + i;
        int pos = row & (L_-1);
        float o[4] = {acc[i][0], acc[i][1], acc[i][2], acc[i][3]};
        if (xposMode) {
            float sgn = (xposMode == 1) ? 1.0f : -1.0f;
            #pragma unroll
            for (int p = 0; p < 2; ++p) {
                int c  = c0 + 2*p;          // even col (colOff==0 for Q/K)
                int ii = c >> 1;            // 0..31
                float sv   = (2.0f*ii + 0.4f*HD_) / (1.4f*HD_);
                float sc   = powf(sv, sgn * (float)pos * (1.0f/512.0f));
                float invf = powf(10000.0f, -(float)ii * (1.0f/32.0f));
                float ang  = (float)pos * invf;
                float s, co; sincosf(ang, &s, &co);
                float x0 = o[2*p], x1 = o[2*p+1];
                o[2*p]   = (x0*co - x1*s) * sc;
                o[2*p+1] = (x1*co + x0*s) * sc;
            }
        }
        int ldo = (xposMode == 0) ? VD_ : HD_;
        *(float4*)&Out[(size_t)row*ldo + colOff + c0] = make_float4(o[0],o[1],o[2],o[3]);
    }
}

// column offset helper: thread covers 8 float4s at ((tid&3)*4 + v4*16)
__device__ __forceinline__ int voff(int tid, int v4) { return ((tid & 3) << 2) + (v4 << 4); }

// -------------------------------------------------------------------------
// K2: per-chunk decayed partial sums  P_t[h][v] = sum_j gamma^(63-j) k_j[h] v_j[v]
// grid B*NC, 256 threads
// -------------------------------------------------------------------------
__global__ __launch_bounds__(256) void k_partial(
    const float* __restrict__ Kf, const float* __restrict__ Vf, float* __restrict__ P)
{
    const int blk = blockIdx.x;
    const int bb = blk / NC_, t = blk % NC_;
    __shared__ float Ks[64][64];
    __shared__ float Vs[64][128];
    const int tid = threadIdx.x;
    const size_t rowBase = (size_t)bb*L_ + (size_t)t*C_;

    #pragma unroll
    for (int it = 0; it < 4; ++it) {
        int idx = tid + it*256;                    // 0..1023
        int j = idx >> 4, h = (idx & 15) << 2;
        *(float4*)&Ks[j][h] = *(const float4*)&Kf[(rowBase + j)*HD_ + h];
    }
    #pragma unroll
    for (int it = 0; it < 8; ++it) {
        int idx = tid + it*256;                    // 0..2047
        int j = idx >> 5, v = (idx & 31) << 2;
        *(float4*)&Vs[j][v] = *(const float4*)&Vf[(rowBase + j)*VD_ + v];
    }
    __syncthreads();

    const int h = tid >> 2;
    float acc[32] = {};
    float w = 1.0f;                                 // gamma^(63-j), j=63 downward
    for (int j = 63; j >= 0; --j) {
        float kv = Ks[j][h] * w;
        #pragma unroll
        for (int v4 = 0; v4 < 8; ++v4) {
            float4 v = *(const float4*)&Vs[j][voff(tid, v4)];
            acc[v4*4+0] = fmaf(kv, v.x, acc[v4*4+0]);
            acc[v4*4+1] = fmaf(kv, v.y, acc[v4*4+1]);
            acc[v4*4+2] = fmaf(kv, v.z, acc[v4*4+2]);
            acc[v4*4+3] = fmaf(kv, v.w, acc[v4*4+3]);
        }
        w *= GAMMA_;
    }
    float* Pp = &P[((size_t)blk*HD_ + h)*VD_];
    #pragma unroll
    for (int v4 = 0; v4 < 8; ++v4)
        *(float4*)&Pp[voff(tid, v4)] = make_float4(acc[v4*4+0],acc[v4*4+1],acc[v4*4+2],acc[v4*4+3]);
}

// -------------------------------------------------------------------------
// K3a: state from 16-chunk window of P, then cross-chunk output (WRITES d_out)
// out[i][v] = gamma^(i+1) * sum_h q_i[h] * S_t[h][v]
// -------------------------------------------------------------------------
__global__ __launch_bounds__(256) void k_cross(
    const float* __restrict__ Qf, const float* __restrict__ P, float* __restrict__ Out)
{
    const int blk = blockIdx.x;
    const int bb = blk / NC_, t = blk % NC_;
    __shared__ float Ss[64][128];
    const int tid = threadIdx.x;
    const float gC = powf(GAMMA_, (float)C_);       // gamma^64 ~ 0.131

    {   // build S_t = sum_{s<t} gC^(t-1-s) P_s  (16-chunk window; tail < 1e-13 rel)
        const int h = tid >> 2;
        float acc[32] = {};
        int s0 = t - 16; if (s0 < 0) s0 = 0;
        float w = 1.0f;
        for (int s = t-1; s >= s0; --s) {
            const float* Pp = &P[(((size_t)bb*NC_ + s)*HD_ + h)*VD_];
            #pragma unroll
            for (int v4 = 0; v4 < 8; ++v4) {
                float4 p = *(const float4*)&Pp[voff(tid, v4)];
                acc[v4*4+0] = fmaf(w, p.x, acc[v4*4+0]);
                acc[v4*4+1] = fmaf(w, p.y, acc[v4*4+1]);
                acc[v4*4+2] = fmaf(w, p.z, acc[v4*4+2]);
                acc[v4*4+3] = fmaf(w, p.w, acc[v4*4+3]);
            }
            w *= gC;
        }
        #pragma unroll
        for (int v4 = 0; v4 < 8; ++v4)
            *(float4*)&Ss[h][voff(tid, v4)] = make_float4(acc[v4*4+0],acc[v4*4+1],acc[v4*4+2],acc[v4*4+3]);
    }
    __syncthreads();

    const int i = tid >> 2;
    const size_t qrow = (size_t)bb*L_ + (size_t)t*C_ + i;
    float o[32] = {};
    for (int hh = 0; hh < 64; ++hh) {
        float q = Qf[qrow*HD_ + hh];
        #pragma unroll
        for (int v4 = 0; v4 < 8; ++v4) {
            float4 s4 = *(const float4*)&Ss[hh][voff(tid, v4)];
            o[v4*4+0] = fmaf(q, s4.x, o[v4*4+0]);
            o[v4*4+1] = fmaf(q, s4.y, o[v4*4+1]);
            o[v4*4+2] = fmaf(q, s4.z, o[v4*4+2]);
            o[v4*4+3] = fmaf(q, s4.w, o[v4*4+3]);
        }
    }
    const float g = powf(GAMMA_, (float)(i+1));
    float* Op = &Out[qrow*VD_];
    #pragma unroll
    for (int v4 = 0; v4 < 8; ++v4)
        *(float4*)&Op[voff(tid, v4)] = make_float4(g*o[v4*4+0],g*o[v4*4+1],g*o[v4*4+2],g*o[v4*4+3]);
}

// -------------------------------------------------------------------------
// K3b: intra-chunk  A = (Q Kt * D_local), out += A @ V   (RMW into d_out)
// A stored LDS with (j+i)&63 rotation to avoid 16-way broadcast conflicts.
// -------------------------------------------------------------------------
#define ASWZ(i, j) Asm[i][((j) + (i)) & 63]

__global__ __launch_bounds__(256) void k_intra(
    const float* __restrict__ Qf, const float* __restrict__ Kf,
    const float* __restrict__ Vf, float* __restrict__ Out)
{
    const int blk = blockIdx.x;
    const int bb = blk / NC_, t = blk % NC_;
    __shared__ float Ks[64][64];
    __shared__ float Vs[64][128];
    __shared__ float Asm[64][64];
    const int tid = threadIdx.x;
    const size_t rowBase = (size_t)bb*L_ + (size_t)t*C_;

    #pragma unroll
    for (int it = 0; it < 4; ++it) {
        int idx = tid + it*256;
        int j = idx >> 4, h = (idx & 15) << 2;
        *(float4*)&Ks[j][h] = *(const float4*)&Kf[(rowBase + j)*HD_ + h];
    }
    #pragma unroll
    for (int it = 0; it < 8; ++it) {
        int idx = tid + it*256;
        int j = idx >> 5, v = (idx & 31) << 2;
        *(float4*)&Vs[j][v] = *(const float4*)&Vf[(rowBase + j)*VD_ + v];
    }
    __syncthreads();

    {   // phase A: scores
        const int i = tid >> 2, jj = tid & 3;
        float4 q[16];
        #pragma unroll
        for (int h4 = 0; h4 < 16; ++h4)
            q[h4] = *(const float4*)&Qf[(rowBase + i)*HD_ + (h4<<2)];
        const float l2g = log2f(GAMMA_);
        for (int j = jj; j < 64; j += 4) {
            float a = 0.0f;
            if (j <= i) {
                float dot = 0.0f;
                #pragma unroll
                for (int h4 = 0; h4 < 16; ++h4) {
                    float4 k4 = *(const float4*)&Ks[j][h4<<2];
                    dot = fmaf(q[h4].x, k4.x, dot);
                    dot = fmaf(q[h4].y, k4.y, dot);
                    dot = fmaf(q[h4].z, k4.z, dot);
                    dot = fmaf(q[h4].w, k4.w, dot);
                }
                a = dot * exp2f((float)(i - j) * l2g);
            }
            ASWZ(i, j) = a;
        }
    }
    __syncthreads();

    const int i = tid >> 2;
    float o[32] = {};
    for (int j = 0; j <= i; ++j) {
        float a = ASWZ(i, j);
        #pragma unroll
        for (int v4 = 0; v4 < 8; ++v4) {
            float4 v = *(const float4*)&Vs[j][voff(tid, v4)];
            o[v4*4+0] = fmaf(a, v.x, o[v4*4+0]);
            o[v4*4+1] = fmaf(a, v.y, o[v4*4+1]);
            o[v4*4+2] = fmaf(a, v.z, o[v4*4+2]);
            o[v4*4+3] = fmaf(a, v.w, o[v4*4+3]);
        }
    }
    float* Op = &Out[(rowBase + i)*VD_];
    #pragma unroll
    for (int v4 = 0; v4 < 8; ++v4) {
        float4 cur = *(const float4*)&Op[voff(tid, v4)];
        cur.x += o[v4*4+0]; cur.y += o[v4*4+1]; cur.z += o[v4*4+2]; cur.w += o[v4*4+3];
        *(float4*)&Op[voff(tid, v4)] = cur;
    }
}

extern "C" void kernel_launch(void* const* d_in, const int* in_sizes, int n_in,
                              void* d_out, int out_size, void* d_ws, size_t ws_size,
                              hipStream_t stream)
{
    const float* X  = (const float*)d_in[0];
    const float* WQ = (const float*)d_in[1];
    const float* WK = (const float*)d_in[2];
    const float* WV = (const float*)d_in[3];
    float* out = (float*)d_out;
    float* ws  = (float*)d_ws;

    float* Qf = ws;                                   // B*L*64   = 1,048,576 f
    float* Kf = Qf + (size_t)B_*L_*HD_;               // B*L*64
    float* Vf = Kf + (size_t)B_*L_*HD_;               // B*L*128  = 2,097,152 f
    float* P  = Vf + (size_t)B_*L_*VD_;               // B*NC*64*128 = 2,097,152 f
    // total ws use: 24 MB

    dim3 g1(256, 4);
    k_proj<<<g1, 256, 0, stream>>>(X, WQ, WK, WV, Qf, Kf, Vf);
    k_partial<<<B_*NC_, 256, 0, stream>>>(Kf, Vf, P);
    k_cross  <<<B_*NC_, 256, 0, stream>>>(Qf, P, out);
    k_intra  <<<B_*NC_, 256, 0, stream>>>(Qf, Kf, Vf, out);
}

// Round 2
// 75.226 us; speedup vs baseline: 1.8225x; 1.8225x over previous
//
#include <hip/hip_runtime.h>
#include <math.h>

#define B_ 4
#define L_ 4096
#define D_ 512
#define HD_ 64
#define VD_ 128
#define C_ 64
#define NC_ (L_/C_)
#define GAMMA_ 0.96875f

typedef __attribute__((ext_vector_type(8))) short bf16x8;
typedef __attribute__((ext_vector_type(4))) float f32x4;
typedef unsigned short u16;
typedef unsigned int u32;

static __device__ __forceinline__ u16 f2b(float f) {   // f32 -> bf16 RNE
    u32 u = __float_as_uint(f);
    u32 r = (u + 0x7FFFu + ((u >> 16) & 1u)) >> 16;
    return (u16)r;
}

// -------------------------------------------------------------------------
// K0: prep — transpose+convert W into Wt[256 n][512 k] bf16.
// n<64: WQ col n | n<128: WK col n-64 | else: WV col n-128
// -------------------------------------------------------------------------
__global__ __launch_bounds__(512) void k_prep(
    const float* __restrict__ WQ, const float* __restrict__ WK,
    const float* __restrict__ WV, u16* __restrict__ Wt)
{
    const int n = blockIdx.x;       // 0..255
    const int k = threadIdx.x;      // 0..511
    float v;
    if (n < 64)       v = WQ[(size_t)k*64  + n];
    else if (n < 128) v = WK[(size_t)k*64  + (n-64)];
    else              v = WV[(size_t)k*128 + (n-128)];
    Wt[(size_t)n*512 + k] = f2b(v);
}

// -------------------------------------------------------------------------
// K1: MFMA projection. C[16384 x 256] = X[16384 x 512] @ Wt^T, bf16 inputs,
// f32 acc. BM=64, BN=256 (full N -> X read once), BK=64, 8 waves, wave tile
// 64x32 (4 m-frags x 2 n-frags of 16x16x32). XOR-swizzled LDS (rows of
// 128 B would otherwise 16-way conflict on ds_read_b128). xPos epilogue via
// shfl_xor(1) rotary-pair exchange; mode is wave-uniform.
// -------------------------------------------------------------------------
__global__ __launch_bounds__(512) void k_projm(
    const float* __restrict__ X, const u16* __restrict__ Wt,
    float* __restrict__ Qf, float* __restrict__ Kf, float* __restrict__ Vf)
{
    __shared__ __align__(16) u16 At[64*64];    // [row][k] bf16, col16 ^= row&7
    __shared__ __align__(16) u16 Bt[256*64];   // [n][k]  bf16, col16 ^= n&7

    const int tid  = threadIdx.x;
    const int lane = tid & 63;
    const int wave = tid >> 6;                 // 0..7
    const int row0 = blockIdx.x * 64;

    // A staging: thread -> (row=tid>>3, col16=tid&7) : 8 f32 -> 8 bf16
    const int ar = tid >> 3, ac = tid & 7;
    const float* gA = X + (size_t)(row0 + ar)*D_ + ac*8;
    // B staging: 4 chunks: q=tid+it*512 -> (n=q>>3, c=q&7) : 8 bf16
    float4 a0 = *(const float4*)(gA + 0);
    float4 a1 = *(const float4*)(gA + 4);
    bf16x8 b[4];
    #pragma unroll
    for (int it = 0; it < 4; ++it) {
        int q = tid + it*512; int n = q >> 3, c = q & 7;
        b[it] = *(const bf16x8*)(Wt + (size_t)n*512 + c*8);
    }

    f32x4 acc[4][2] = {};

    for (int t = 0; t < 8; ++t) {
        __syncthreads();                       // LDS free from prev readers
        {
            bf16x8 av;
            av[0]=(short)f2b(a0.x); av[1]=(short)f2b(a0.y);
            av[2]=(short)f2b(a0.z); av[3]=(short)f2b(a0.w);
            av[4]=(short)f2b(a1.x); av[5]=(short)f2b(a1.y);
            av[6]=(short)f2b(a1.z); av[7]=(short)f2b(a1.w);
            *(bf16x8*)&At[ar*64 + (ac ^ (ar & 7))*8] = av;
            #pragma unroll
            for (int it = 0; it < 4; ++it) {
                int q = tid + it*512; int n = q >> 3, c = q & 7;
                *(bf16x8*)&Bt[n*64 + (c ^ (n & 7))*8] = b[it];
            }
        }
        __syncthreads();
        if (t < 7) {                           // prefetch next K-step (overlaps MFMA)
            a0 = *(const float4*)(gA + (t+1)*64);
            a1 = *(const float4*)(gA + (t+1)*64 + 4);
            #pragma unroll
            for (int it = 0; it < 4; ++it) {
                int q = tid + it*512; int n = q >> 3, c = q & 7;
                b[it] = *(const bf16x8*)(Wt + (size_t)n*512 + (t+1)*64 + c*8);
            }
        }
        #pragma unroll
        for (int ks = 0; ks < 2; ++ks) {
            bf16x8 af[4], bfr[2];
            #pragma unroll
            for (int m = 0; m < 4; ++m) {
                int r = m*16 + (lane & 15);
                int c = ks*4 + (lane >> 4);
                af[m] = *(const bf16x8*)&At[r*64 + (c ^ (r & 7))*8];
            }
            #pragma unroll
            for (int n = 0; n < 2; ++n) {
                int r = wave*32 + n*16 + (lane & 15);
                int c = ks*4 + (lane >> 4);
                bfr[n] = *(const bf16x8*)&Bt[r*64 + (c ^ (r & 7))*8];
            }
            #pragma unroll
            for (int m = 0; m < 4; ++m)
                #pragma unroll
                for (int n = 0; n < 2; ++n)
                    acc[m][n] = __builtin_amdgcn_mfma_f32_16x16x32_bf16(af[m], bfr[n], acc[m][n], 0, 0, 0);
        }
    }

    // epilogue: C row = m*16+(lane>>4)*4+r, col = wave*32+n*16+(lane&15)
    const int mode = (wave < 2) ? 0 : (wave < 4) ? 1 : 2;   // Q / K / V
    const float sgn = (mode == 0) ? 1.0f : -1.0f;
    #pragma unroll
    for (int m = 0; m < 4; ++m)
        #pragma unroll
        for (int n = 0; n < 2; ++n)
            #pragma unroll
            for (int r = 0; r < 4; ++r) {
                int row = row0 + m*16 + ((lane >> 4) << 2) + r;
                int col = wave*32 + n*16 + (lane & 15);
                float v = acc[m][n][r];
                float p = __shfl_xor(v, 1, 64);
                if (mode < 2) {
                    int c  = col & 63;
                    int ii = c >> 1;
                    int pos = row & (L_ - 1);
                    float sv   = (2.0f*ii + 0.4f*HD_) * (1.0f/(1.4f*HD_));
                    float sc   = exp2f(sgn * __log2f(sv) * (float)pos * (1.0f/512.0f));
                    float invf = exp2f((float)ii * (-13.287712379549449f/32.0f));
                    float ang  = (float)pos * invf;
                    float s, co; sincosf(ang, &s, &co);
                    float o = ((col & 1) == 0) ? (v*co - p*s) : (v*co + p*s);
                    o *= sc;
                    if (mode == 0) Qf[(size_t)row*HD_ + c] = o;
                    else           Kf[(size_t)row*HD_ + c] = o;
                } else {
                    Vf[(size_t)row*VD_ + (col - 128)] = v;
                }
            }
}

// -------------------------------------------------------------------------
// K2: per-chunk decayed partials P_t[h][v] = sum_j gamma^(63-j) k_j[h] v_j[v]
// 512 thr, 4x4 register micro-tile (2 B of LDS per FMA).
// -------------------------------------------------------------------------
__global__ __launch_bounds__(512) void k_partial(
    const float* __restrict__ Kf, const float* __restrict__ Vf, float* __restrict__ P)
{
    __shared__ float Ks[64][64];    // [j][h]
    __shared__ float Vs[64][128];   // [j][v]
    const int tid = threadIdx.x;
    const int blk = blockIdx.x;
    const int bb = blk >> 6, t = blk & 63;
    const size_t rowBase = (size_t)bb*L_ + (size_t)t*C_;

    {
        int j = tid >> 3, h = (tid & 7) * 8;
        *(float4*)&Ks[j][h]   = *(const float4*)&Kf[(rowBase + j)*HD_ + h];
        *(float4*)&Ks[j][h+4] = *(const float4*)&Kf[(rowBase + j)*HD_ + h + 4];
        int v = (tid & 7) * 16;
        #pragma unroll
        for (int q = 0; q < 4; ++q)
            *(float4*)&Vs[j][v + q*4] = *(const float4*)&Vf[(rowBase + j)*VD_ + v + q*4];
    }
    __syncthreads();

    const int h0 = (tid >> 5) << 2;        // 0,4,..,60
    const int v0 = (tid & 31) << 2;        // 0,4,..,124
    float acc[4][4] = {};
    float w = 1.0f;
    for (int j = 63; j >= 0; --j) {
        float4 kv = *(const float4*)&Ks[j][h0];
        float4 vv = *(const float4*)&Vs[j][v0];
        float kw[4] = {kv.x*w, kv.y*w, kv.z*w, kv.w*w};
        #pragma unroll
        for (int a = 0; a < 4; ++a) {
            acc[a][0] = fmaf(kw[a], vv.x, acc[a][0]);
            acc[a][1] = fmaf(kw[a], vv.y, acc[a][1]);
            acc[a][2] = fmaf(kw[a], vv.z, acc[a][2]);
            acc[a][3] = fmaf(kw[a], vv.w, acc[a][3]);
        }
        w *= GAMMA_;
    }
    #pragma unroll
    for (int a = 0; a < 4; ++a)
        *(float4*)&P[((size_t)blk*HD_ + h0 + a)*VD_ + v0] =
            make_float4(acc[a][0], acc[a][1], acc[a][2], acc[a][3]);
}

// -------------------------------------------------------------------------
// K3: cross-chunk — build S_t from 16-chunk P window, out = gamma^(i+1) q.S
// (writes ALL of d_out). 4x4 micro-tile, QsT transposed in LDS.
// -------------------------------------------------------------------------
__global__ __launch_bounds__(512) void k_cross(
    const float* __restrict__ Qf, const float* __restrict__ P, float* __restrict__ Out)
{
    __shared__ float Ss[64][128];   // [h][v]
    __shared__ float QsT[64][64];   // [h][i]
    const int tid = threadIdx.x;
    const int blk = blockIdx.x;
    const int bb = blk >> 6, t = blk & 63;
    const size_t rowBase = (size_t)bb*L_ + (size_t)t*C_;
    const float gC = 0.13108252f;   // gamma^64

    {   // stage Q transposed
        int r = tid >> 3, c0 = (tid & 7) * 8;
        float4 qa = *(const float4*)&Qf[(rowBase + r)*HD_ + c0];
        float4 qb = *(const float4*)&Qf[(rowBase + r)*HD_ + c0 + 4];
        QsT[c0+0][r] = qa.x; QsT[c0+1][r] = qa.y; QsT[c0+2][r] = qa.z; QsT[c0+3][r] = qa.w;
        QsT[c0+4][r] = qb.x; QsT[c0+5][r] = qb.y; QsT[c0+6][r] = qb.z; QsT[c0+7][r] = qb.w;
    }
    const int h0 = (tid >> 5) << 2;
    const int v0 = (tid & 31) << 2;
    {   // build S window
        float acc[4][4] = {};
        int s0 = t - 16; if (s0 < 0) s0 = 0;
        float w = 1.0f;
        for (int s = t-1; s >= s0; --s) {
            const float* Pp = &P[(((size_t)bb*NC_ + s)*HD_)*VD_];
            #pragma unroll
            for (int a = 0; a < 4; ++a) {
                float4 pv = *(const float4*)&Pp[(size_t)(h0+a)*VD_ + v0];
                acc[a][0] = fmaf(w, pv.x, acc[a][0]);
                acc[a][1] = fmaf(w, pv.y, acc[a][1]);
                acc[a][2] = fmaf(w, pv.z, acc[a][2]);
                acc[a][3] = fmaf(w, pv.w, acc[a][3]);
            }
            w *= gC;
        }
        #pragma unroll
        for (int a = 0; a < 4; ++a)
            *(float4*)&Ss[h0+a][v0] = make_float4(acc[a][0],acc[a][1],acc[a][2],acc[a][3]);
    }
    __syncthreads();

    const int i0 = (tid >> 5) << 2;
    float acc[4][4] = {};
    for (int h = 0; h < 64; ++h) {
        float4 qv = *(const float4*)&QsT[h][i0];
        float4 sv = *(const float4*)&Ss[h][v0];
        float qa[4] = {qv.x, qv.y, qv.z, qv.w};
        #pragma unroll
        for (int a = 0; a < 4; ++a) {
            acc[a][0] = fmaf(qa[a], sv.x, acc[a][0]);
            acc[a][1] = fmaf(qa[a], sv.y, acc[a][1]);
            acc[a][2] = fmaf(qa[a], sv.z, acc[a][2]);
            acc[a][3] = fmaf(qa[a], sv.w, acc[a][3]);
        }
    }
    const float l2g = -0.04580369f; // log2(gamma)
    #pragma unroll
    for (int a = 0; a < 4; ++a) {
        float g = exp2f((float)(i0 + a + 1) * l2g);
        *(float4*)&Out[(rowBase + i0 + a)*VD_ + v0] =
            make_float4(g*acc[a][0], g*acc[a][1], g*acc[a][2], g*acc[a][3]);
    }
}

// -------------------------------------------------------------------------
// K4: intra-chunk — A = (QK^T (.) D_local) stored transposed, out += A @ V.
// LDS = 16+32+16 = 64 KB exactly.
// -------------------------------------------------------------------------
__global__ __launch_bounds__(512) void k_intra(
    const float* __restrict__ Qf, const float* __restrict__ Kf,
    const float* __restrict__ Vf, float* __restrict__ Out)
{
    __shared__ float Ks[64][64];    // [j][h]
    __shared__ float Vs[64][128];   // [j][v]
    __shared__ float AsT[64][64];   // [j][i]
    const int tid = threadIdx.x;
    const int blk = blockIdx.x;
    const int bb = blk >> 6, t = blk & 63;
    const size_t rowBase = (size_t)bb*L_ + (size_t)t*C_;

    {
        int j = tid >> 3, h = (tid & 7) * 8;
        *(float4*)&Ks[j][h]   = *(const float4*)&Kf[(rowBase + j)*HD_ + h];
        *(float4*)&Ks[j][h+4] = *(const float4*)&Kf[(rowBase + j)*HD_ + h + 4];
        int v = (tid & 7) * 16;
        #pragma unroll
        for (int q = 0; q < 4; ++q)
            *(float4*)&Vs[j][v + q*4] = *(const float4*)&Vf[(rowBase + j)*VD_ + v + q*4];
    }
    __syncthreads();

    {   // scores: thread (i = tid>>3, jj = tid&7), 8 j's each
        const int i = tid >> 3, jj = tid & 7;
        float4 q[16];
        #pragma unroll
        for (int h4 = 0; h4 < 16; ++h4)
            q[h4] = *(const float4*)&Qf[(rowBase + i)*HD_ + (h4 << 2)];
        const float l2g = -0.04580369f;
        #pragma unroll
        for (int js = 0; js < 8; ++js) {
            int j = jj + js*8;
            float a = 0.0f;
            if (j <= i) {
                float dot = 0.0f;
                #pragma unroll
                for (int h4 = 0; h4 < 16; ++h4) {
                    float4 k4 = *(const float4*)&Ks[j][h4 << 2];
                    dot = fmaf(q[h4].x, k4.x, dot);
                    dot = fmaf(q[h4].y, k4.y, dot);
                    dot = fmaf(q[h4].z, k4.z, dot);
                    dot = fmaf(q[h4].w, k4.w, dot);
                }
                a = dot * exp2f((float)(i - j) * l2g);
            }
            AsT[j][i] = a;
        }
    }
    __syncthreads();

    const int i0 = (tid >> 5) << 2;
    const int v0 = (tid & 31) << 2;
    float acc[4][4] = {};
    for (int j = 0; j <= i0 + 3; ++j) {       // entries with j>i are stored 0
        float4 av = *(const float4*)&AsT[j][i0];
        float4 vv = *(const float4*)&Vs[j][v0];
        float aa[4] = {av.x, av.y, av.z, av.w};
        #pragma unroll
        for (int a = 0; a < 4; ++a) {
            acc[a][0] = fmaf(aa[a], vv.x, acc[a][0]);
            acc[a][1] = fmaf(aa[a], vv.y, acc[a][1]);
            acc[a][2] = fmaf(aa[a], vv.z, acc[a][2]);
            acc[a][3] = fmaf(aa[a], vv.w, acc[a][3]);
        }
    }
    #pragma unroll
    for (int a = 0; a < 4; ++a) {
        float* Op = &Out[(rowBase + i0 + a)*VD_ + v0];
        float4 cur = *(const float4*)Op;
        cur.x += acc[a][0]; cur.y += acc[a][1]; cur.z += acc[a][2]; cur.w += acc[a][3];
        *(float4*)Op = cur;
    }
}

extern "C" void kernel_launch(void* const* d_in, const int* in_sizes, int n_in,
                              void* d_out, int out_size, void* d_ws, size_t ws_size,
                              hipStream_t stream)
{
    const float* X  = (const float*)d_in[0];
    const float* WQ = (const float*)d_in[1];
    const float* WK = (const float*)d_in[2];
    const float* WV = (const float*)d_in[3];
    float* out = (float*)d_out;
    float* ws  = (float*)d_ws;

    float* Qf = ws;                           // 1,048,576 f (4 MB)
    float* Kf = Qf + (size_t)B_*L_*HD_;       // 4 MB
    float* Vf = Kf + (size_t)B_*L_*HD_;       // 8 MB
    float* P  = Vf + (size_t)B_*L_*VD_;       // 8 MB
    u16*   Wt = (u16*)P;                      // 256 KB, aliases P: dead before k_partial writes P

    k_prep   <<<256, 512, 0, stream>>>(WQ, WK, WV, Wt);
    k_projm  <<<256, 512, 0, stream>>>(X, Wt, Qf, Kf, Vf);
    k_partial<<<B_*NC_, 512, 0, stream>>>(Kf, Vf, P);
    k_cross  <<<B_*NC_, 512, 0, stream>>>(Qf, P, out);
    k_intra  <<<B_*NC_, 512, 0, stream>>>(Qf, Kf, Vf, out);
}

// Round 3
// 41.712 us; speedup vs baseline: 3.2869x; 1.8035x over previous
//
#include <hip/hip_runtime.h>
#include <math.h>

#define B_ 4
#define L_ 4096
#define D_ 512
#define HD_ 64
#define VD_ 128
#define C_ 64
#define NC_ (L_/C_)
#define GAMMA_ 0.96875f
#define L2G_ (-0.045803595f)        // log2(gamma)
#define GC_  (0.13108252f)          // gamma^64

typedef __attribute__((ext_vector_type(8))) short bf16x8;
typedef __attribute__((ext_vector_type(4))) float f32x4;
typedef unsigned short u16;
typedef unsigned int u32;

static __device__ __forceinline__ u16 f2b(float f) {   // f32 -> bf16 RNE
    u32 u = __float_as_uint(f);
    return (u16)((u + 0x7FFFu + ((u >> 16) & 1u)) >> 16);
}
static __device__ __forceinline__ float b2f(u16 h) {
    return __uint_as_float((u32)h << 16);
}

// -------------------------------------------------------------------------
// K0: W -> Wt[256 n][512 k] bf16 (transposed, Q|K|V concatenated)
// -------------------------------------------------------------------------
__global__ __launch_bounds__(512) void k_prep(
    const float* __restrict__ WQ, const float* __restrict__ WK,
    const float* __restrict__ WV, u16* __restrict__ Wt)
{
    const int n = blockIdx.x, k = threadIdx.x;
    float v;
    if (n < 64)       v = WQ[(size_t)k*64  + n];
    else if (n < 128) v = WK[(size_t)k*64  + (n-64)];
    else              v = WV[(size_t)k*128 + (n-128)];
    Wt[(size_t)n*512 + k] = f2b(v);
}

// -------------------------------------------------------------------------
// K1: projection GEMM (BM=64 == one chunk) + xPos epilogue + in-block
// P_t = K^T diag(gamma^(63-j)) V via MFMA. Outputs (all bf16):
//   Qb[l][h], Kb[l][h] (xPos applied), Vt[chunk][v][j], Pb[chunk][v][h]
// -------------------------------------------------------------------------
__global__ __launch_bounds__(512) void k_projm(
    const float* __restrict__ X, const u16* __restrict__ Wt,
    u16* __restrict__ Qb, u16* __restrict__ Kb,
    u16* __restrict__ Vt, u16* __restrict__ Pb)
{
    __shared__ __align__(16) u16 lds[20480];   // 40 KB, aliased across phases
    u16* At = lds;            // [64][64]  X tile (bf16, swizzled)
    u16* Bt = lds + 4096;     // [256][64] W tile

    const int tid  = threadIdx.x;
    const int lane = tid & 63;
    const int ln15 = lane & 15, ln4 = lane >> 4;
    const int wave = tid >> 6;
    const int row0 = blockIdx.x * 64;

    const int ar = tid >> 3, ac = tid & 7;
    const float* gA = X + (size_t)(row0 + ar)*D_ + ac*8;
    float4 a0 = *(const float4*)(gA + 0);
    float4 a1 = *(const float4*)(gA + 4);
    bf16x8 b[4];
    #pragma unroll
    for (int it = 0; it < 4; ++it) {
        int q = tid + it*512; int n = q >> 3, c = q & 7;
        b[it] = *(const bf16x8*)(Wt + (size_t)n*512 + c*8);
    }

    f32x4 acc[4][2] = {};

    for (int t = 0; t < 8; ++t) {
        __syncthreads();
        {
            bf16x8 av;
            av[0]=(short)f2b(a0.x); av[1]=(short)f2b(a0.y);
            av[2]=(short)f2b(a0.z); av[3]=(short)f2b(a0.w);
            av[4]=(short)f2b(a1.x); av[5]=(short)f2b(a1.y);
            av[6]=(short)f2b(a1.z); av[7]=(short)f2b(a1.w);
            *(bf16x8*)&At[ar*64 + ((ac ^ (ar & 7)) << 3)] = av;
            #pragma unroll
            for (int it = 0; it < 4; ++it) {
                int q = tid + it*512; int n = q >> 3, c = q & 7;
                *(bf16x8*)&Bt[n*64 + ((c ^ (n & 7)) << 3)] = b[it];
            }
        }
        __syncthreads();
        if (t < 7) {
            a0 = *(const float4*)(gA + (t+1)*64);
            a1 = *(const float4*)(gA + (t+1)*64 + 4);
            #pragma unroll
            for (int it = 0; it < 4; ++it) {
                int q = tid + it*512; int n = q >> 3, c = q & 7;
                b[it] = *(const bf16x8*)(Wt + (size_t)n*512 + (t+1)*64 + c*8);
            }
        }
        #pragma unroll
        for (int ks = 0; ks < 2; ++ks) {
            bf16x8 af[4], bfr[2];
            #pragma unroll
            for (int m = 0; m < 4; ++m) {
                int r = m*16 + ln15;
                int c = (ks*4 + ln4) ^ (r & 7);
                af[m] = *(const bf16x8*)&At[r*64 + (c << 3)];
            }
            #pragma unroll
            for (int n = 0; n < 2; ++n) {
                int r = wave*32 + n*16 + ln15;
                int c = (ks*4 + ln4) ^ (r & 7);
                bfr[n] = *(const bf16x8*)&Bt[r*64 + (c << 3)];
            }
            #pragma unroll
            for (int m = 0; m < 4; ++m)
                #pragma unroll
                for (int n = 0; n < 2; ++n)
                    acc[m][n] = __builtin_amdgcn_mfma_f32_16x16x32_bf16(af[m], bfr[n], acc[m][n], 0, 0, 0);
        }
    }
    __syncthreads();                         // GEMM reads done; re-carve LDS

    u16* Qb_l = lds;          // [64][64]   swizzled
    u16* Kb_l = lds + 4096;   // [64][64]   swizzled
    u16* Kd_l = lds + 8192;   // [64 h][64 j] decayed K^T, swizzled
    u16* Vt_l = lds + 12288;  // [128 v][64 j] V^T, swizzled

    const int mode = (wave < 2) ? 0 : (wave < 4) ? 1 : 2;   // Q / K / V
    const float sgn = (mode == 0) ? 1.0f : -1.0f;
    #pragma unroll
    for (int m = 0; m < 4; ++m) {
        const int j0 = m*16 + (ln4 << 2);          // chunk-row base for this frag
        const int cj = j0 >> 3;
        #pragma unroll
        for (int n = 0; n < 2; ++n) {
            const int col = wave*32 + n*16 + ln15;
            u16 pk[4];
            #pragma unroll
            for (int r = 0; r < 4; ++r) {
                int jrow = j0 + r;
                int row  = row0 + jrow;
                int pos  = row & (L_ - 1);
                float v = acc[m][n][r];
                float p = __shfl_xor(v, 1, 64);
                if (mode < 2) {
                    int h  = col & 63;
                    int ii = h >> 1;
                    float sv   = (2.0f*ii + 0.4f*HD_) * (1.0f/(1.4f*HD_));
                    float sc   = exp2f(sgn * __log2f(sv) * (float)pos * (1.0f/512.0f));
                    float invf = exp2f((float)ii * (-13.287712379549449f/32.0f));
                    float ang  = (float)pos * invf;
                    float s, co; sincosf(ang, &s, &co);
                    float o = ((col & 1) == 0) ? (v*co - p*s) : (v*co + p*s);
                    o *= sc;
                    u16 ob = f2b(o);
                    int swz = jrow*64 + (((h >> 3) ^ (jrow & 7)) << 3) + (h & 7);
                    if (mode == 0) Qb_l[swz] = ob;
                    else {
                        Kb_l[swz] = ob;
                        pk[r] = f2b(o * exp2f((float)(63 - jrow) * L2G_));  // decayed
                    }
                } else {
                    pk[r] = f2b(v);
                }
            }
            if (mode == 1) {        // Kd_l[h][j0..j0+3]
                int h = col & 63;
                *(ushort4*)&Kd_l[h*64 + ((cj ^ (h & 7)) << 3) + (j0 & 7)] =
                    make_ushort4(pk[0], pk[1], pk[2], pk[3]);
            } else if (mode == 2) { // Vt_l[v][j0..j0+3]
                int v = col - 128;
                *(ushort4*)&Vt_l[v*64 + ((cj ^ (v & 7)) << 3) + (j0 & 7)] =
                    make_ushort4(pk[0], pk[1], pk[2], pk[3]);
            }
        }
    }
    __syncthreads();

    // flush Qb/Kb/Vt (de-swizzle) while P-MFMA runs
    {
        int i = tid >> 3, c = tid & 7;
        int swz = i*64 + ((c ^ (i & 7)) << 3);
        *(bf16x8*)&Qb[(size_t)(row0 + i)*64 + c*8] = *(const bf16x8*)&Qb_l[swz];
        *(bf16x8*)&Kb[(size_t)(row0 + i)*64 + c*8] = *(const bf16x8*)&Kb_l[swz];
        #pragma unroll
        for (int it = 0; it < 2; ++it) {
            int idx = tid + it*512; int v = idx >> 3, c2 = idx & 7;
            *(bf16x8*)&Vt[(size_t)blockIdx.x*8192 + v*64 + c2*8] =
                *(const bf16x8*)&Vt_l[v*64 + ((c2 ^ (v & 7)) << 3)];
        }
    }
    // P^T[v][h] = sum_j Vt[v][j] * Kd[h][j]
    f32x4 accp[4] = {};
    const int vr = wave;
    #pragma unroll
    for (int ks = 0; ks < 2; ++ks) {
        int rv = vr*16 + ln15;
        bf16x8 av = *(const bf16x8*)&Vt_l[rv*64 + (((ks*4 + ln4) ^ (rv & 7)) << 3)];
        #pragma unroll
        for (int hc = 0; hc < 4; ++hc) {
            int rh = hc*16 + ln15;
            bf16x8 bk = *(const bf16x8*)&Kd_l[rh*64 + (((ks*4 + ln4) ^ (rh & 7)) << 3)];
            accp[hc] = __builtin_amdgcn_mfma_f32_16x16x32_bf16(av, bk, accp[hc], 0, 0, 0);
        }
    }
    __syncthreads();
    u16* Pb_l = lds;          // [128 v][64 h] linear (overwrites Qb_l/Kb_l)
    #pragma unroll
    for (int hc = 0; hc < 4; ++hc)
        #pragma unroll
        for (int r = 0; r < 4; ++r) {
            int v = vr*16 + (ln4 << 2) + r;
            int h = hc*16 + ln15;
            Pb_l[v*64 + h] = f2b(accp[hc][r]);
        }
    __syncthreads();
    #pragma unroll
    for (int it = 0; it < 2; ++it) {
        int idx = tid + it*512;
        *(bf16x8*)&Pb[(size_t)blockIdx.x*8192 + idx*8] = *(const bf16x8*)&Pb_l[idx*8];
    }
}

// -------------------------------------------------------------------------
// K2: per-chunk output (writes ALL of d_out).
//   S^T from 16-chunk Pb window (f32 acc) -> bf16 LDS
//   scores = QK^T (MFMA), decay+mask -> As bf16
//   O = gamma^(i+1) * Q@S  +  As@V^T   (both MFMA ladders, f32 acc)
// -------------------------------------------------------------------------
#define LDSFRAG(buf, rowblk, ks) \
    (*(const bf16x8*)&(buf)[((rowblk)*16 + ln15)*64 + \
        ((((ks)*4 + ln4) ^ ((((rowblk)*16 + ln15)) & 7)) << 3)])

__global__ __launch_bounds__(512) void k_chunk(
    const u16* __restrict__ Qb, const u16* __restrict__ Kb,
    const u16* __restrict__ Vt, const u16* __restrict__ Pb,
    float* __restrict__ Out)
{
    __shared__ __align__(16) u16 Qs[4096];    // [i][h]
    __shared__ __align__(16) u16 Ks_[4096];   // [j][h]
    __shared__ __align__(16) u16 Vs[8192];    // [v][j]
    __shared__ __align__(16) u16 Ss[8192];    // [v][h] = S^T
    __shared__ __align__(16) u16 As[4096];    // [i][j] decayed scores

    const int tid  = threadIdx.x;
    const int lane = tid & 63;
    const int ln15 = lane & 15, ln4 = lane >> 4;
    const int wave = tid >> 6;
    const int blk  = blockIdx.x;
    const int t    = blk & 63;
    const size_t rowBase = (size_t)blk * 64;       // == bb*L + t*64

    {   // stage Q, K, V^T (reg->swizzled LDS)
        int i = tid >> 3, c = tid & 7;
        bf16x8 q = *(const bf16x8*)&Qb[(rowBase + i)*64 + c*8];
        bf16x8 k = *(const bf16x8*)&Kb[(rowBase + i)*64 + c*8];
        *(bf16x8*)&Qs[i*64 + ((c ^ (i & 7)) << 3)] = q;
        *(bf16x8*)&Ks_[i*64 + ((c ^ (i & 7)) << 3)] = k;
        #pragma unroll
        for (int it = 0; it < 2; ++it) {
            int idx = tid + it*512; int v = idx >> 3, c2 = idx & 7;
            bf16x8 vv = *(const bf16x8*)&Vt[(size_t)blk*8192 + v*64 + c2*8];
            *(bf16x8*)&Vs[v*64 + ((c2 ^ (v & 7)) << 3)] = vv;
        }
    }
    {   // S^T build: thread owns (v, 16 h-values)
        int v = tid >> 2, h0 = (tid & 3) * 16;
        float acc[16] = {};
        int nwin = (t < 16) ? t : 16;
        const u16* pb = Pb + (size_t)(blk - 1)*8192 + v*64 + h0;
        float w = 1.0f;
        #pragma unroll 4
        for (int s = 0; s < nwin; ++s) {
            bf16x8 p0 = *(const bf16x8*)(pb - (size_t)s*8192);
            bf16x8 p1 = *(const bf16x8*)(pb - (size_t)s*8192 + 8);
            #pragma unroll
            for (int e = 0; e < 8; ++e) {
                acc[e]   = fmaf(w, b2f((u16)p0[e]), acc[e]);
                acc[8+e] = fmaf(w, b2f((u16)p1[e]), acc[8+e]);
            }
            w *= GC_;
        }
        bf16x8 s0, s1;
        #pragma unroll
        for (int e = 0; e < 8; ++e) { s0[e] = (short)f2b(acc[e]); s1[e] = (short)f2b(acc[8+e]); }
        int c0 = h0 >> 3;
        *(bf16x8*)&Ss[v*64 + ((c0      ^ (v & 7)) << 3)] = s0;
        *(bf16x8*)&Ss[v*64 + (((c0+1) ^ (v & 7)) << 3)] = s1;
    }
    __syncthreads();

    const int fr  = wave & 3;            // i-block
    const int fcp = (wave >> 2) * 2;     // j-block pair
    const int vc  = (wave >> 2) * 4;     // v-block base

    // QK^T
    f32x4 sacc[2] = {};
    #pragma unroll
    for (int ks = 0; ks < 2; ++ks) {
        bf16x8 aq = LDSFRAG(Qs, fr, ks);
        #pragma unroll
        for (int n = 0; n < 2; ++n)
            sacc[n] = __builtin_amdgcn_mfma_f32_16x16x32_bf16(aq, LDSFRAG(Ks_, fcp+n, ks), sacc[n], 0, 0, 0);
    }
    // decay + causal mask -> As (bf16, swizzled)
    #pragma unroll
    for (int n = 0; n < 2; ++n)
        #pragma unroll
        for (int r = 0; r < 4; ++r) {
            int i = fr*16 + (ln4 << 2) + r;
            int j = (fcp+n)*16 + ln15;
            float a = (j <= i) ? sacc[n][r] * exp2f((float)(i - j) * L2G_) : 0.0f;
            As[i*64 + (((j >> 3) ^ (i & 7)) << 3) + (j & 7)] = f2b(a);
        }
    // cross term: O = Q @ S  (then scale by gamma^(i+1))
    f32x4 oacc[4] = {};
    #pragma unroll
    for (int ks = 0; ks < 2; ++ks) {
        bf16x8 aq = LDSFRAG(Qs, fr, ks);
        #pragma unroll
        for (int n = 0; n < 4; ++n)
            oacc[n] = __builtin_amdgcn_mfma_f32_16x16x32_bf16(aq, LDSFRAG(Ss, vc+n, ks), oacc[n], 0, 0, 0);
    }
    float gr[4];
    #pragma unroll
    for (int r = 0; r < 4; ++r)
        gr[r] = exp2f((float)(fr*16 + (ln4 << 2) + r + 1) * L2G_);
    #pragma unroll
    for (int n = 0; n < 4; ++n)
        #pragma unroll
        for (int r = 0; r < 4; ++r)
            oacc[n][r] *= gr[r];
    __syncthreads();
    // intra term: O += As @ V^T
    #pragma unroll
    for (int ks = 0; ks < 2; ++ks) {
        bf16x8 aa = LDSFRAG(As, fr, ks);
        #pragma unroll
        for (int n = 0; n < 4; ++n)
            oacc[n] = __builtin_amdgcn_mfma_f32_16x16x32_bf16(aa, LDSFRAG(Vs, vc+n, ks), oacc[n], 0, 0, 0);
    }
    #pragma unroll
    for (int n = 0; n < 4; ++n)
        #pragma unroll
        for (int r = 0; r < 4; ++r) {
            int i = fr*16 + (ln4 << 2) + r;
            int v = (vc+n)*16 + ln15;
            Out[(rowBase + i)*VD_ + v] = oacc[n][r];
        }
}

extern "C" void kernel_launch(void* const* d_in, const int* in_sizes, int n_in,
                              void* d_out, int out_size, void* d_ws, size_t ws_size,
                              hipStream_t stream)
{
    const float* X  = (const float*)d_in[0];
    const float* WQ = (const float*)d_in[1];
    const float* WK = (const float*)d_in[2];
    const float* WV = (const float*)d_in[3];
    float* out = (float*)d_out;

    u16* Wt = (u16*)d_ws;                       // 256 KB
    u16* Qb = Wt + 131072;                      // 2 MB
    u16* Kb = Qb + 1048576;                     // 2 MB
    u16* Vt = Kb + 1048576;                     // 4 MB
    u16* Pb = Vt + 2097152;                     // 4 MB

    k_prep <<<256, 512, 0, stream>>>(WQ, WK, WV, Wt);
    k_projm<<<256, 512, 0, stream>>>(X, Wt, Qb, Kb, Vt, Pb);
    k_chunk<<<256, 512, 0, stream>>>(Qb, Kb, Vt, Pb, out);
}

// Round 4
// 38.357 us; speedup vs baseline: 3.5744x; 1.0875x over previous
//
#include <hip/hip_runtime.h>
#include <math.h>

#define B_ 4
#define L_ 4096
#define D_ 512
#define HD_ 64
#define VD_ 128
#define C_ 64
#define NC_ (L_/C_)
#define GAMMA_ 0.96875f
#define L2G_ (-0.045803595f)        // log2(gamma)
#define GC_  (0.13108252f)          // gamma^64

typedef __attribute__((ext_vector_type(8))) short bf16x8;
typedef __attribute__((ext_vector_type(4))) float f32x4;
typedef unsigned short u16;
typedef unsigned int u32;

static __device__ __forceinline__ u16 f2b(float f) {   // f32 -> bf16 RNE
    u32 u = __float_as_uint(f);
    return (u16)((u + 0x7FFFu + ((u >> 16) & 1u)) >> 16);
}
static __device__ __forceinline__ float b2f(u16 h) {
    return __uint_as_float((u32)h << 16);
}

// -------------------------------------------------------------------------
// K0: blocks 0..255: W -> Wt[256 n][512 k] bf16 (transposed, Q|K|V concat)
//     blocks 256..511: xPos table T[pos][ii] = {cos*sc, sin*sc, cos/sc, sin/sc}
// -------------------------------------------------------------------------
__global__ __launch_bounds__(512) void k_prep(
    const float* __restrict__ WQ, const float* __restrict__ WK,
    const float* __restrict__ WV, u16* __restrict__ Wt, float4* __restrict__ T)
{
    const int b = blockIdx.x, tid = threadIdx.x;
    if (b < 256) {
        const int n = b, k = tid;
        float v;
        if (n < 64)       v = WQ[(size_t)k*64  + n];
        else if (n < 128) v = WK[(size_t)k*64  + (n-64)];
        else              v = WV[(size_t)k*128 + (n-128)];
        Wt[(size_t)n*512 + k] = f2b(v);
    } else {
        int e = (b - 256)*512 + tid;            // 131072 = 4096 pos x 32 ii
        int pos = e >> 5, ii = e & 31;
        float sv   = (2.0f*ii + 0.4f*HD_) * (1.0f/(1.4f*HD_));
        float sc   = powf(sv, (float)pos * (1.0f/512.0f));
        float invf = powf(10000.0f, -(float)ii * (1.0f/32.0f));
        float ang  = (float)pos * invf;
        float s, c; sincosf(ang, &s, &c);
        T[e] = make_float4(c*sc, s*sc, c/sc, s/sc);
    }
}

// -------------------------------------------------------------------------
// K1: projection GEMM (BM=64 == one chunk, BN=256 full) + xPos via table +
// in-block P_t = K^T diag(gamma^(63-j)) V via MFMA. 1024 thr (16 waves,
// wave tile 64x16 -> 4 waves/SIMD). Outputs (bf16):
//   Qb[l][h], Kb[l][h], Vt[chunk][v][j], Pb[chunk][v][h]
// -------------------------------------------------------------------------
__global__ __launch_bounds__(1024) void k_projm(
    const float* __restrict__ X, const u16* __restrict__ Wt,
    const float4* __restrict__ T,
    u16* __restrict__ Qb, u16* __restrict__ Kb,
    u16* __restrict__ Vt, u16* __restrict__ Pb)
{
    __shared__ __align__(16) u16 lds[20480];   // 40 KB, aliased across phases
    u16* At = lds;            // [64][64]  X tile bf16, swizzled
    u16* Bt = lds + 4096;     // [256][64] W tile

    const int tid  = threadIdx.x;
    const int lane = tid & 63;
    const int ln15 = lane & 15, ln4 = lane >> 4;
    const int wave = tid >> 6;                  // 0..15
    const int row0 = blockIdx.x * 64;

    // A stage: thread -> (r=tid>>4, q=tid&15): one float4 -> ushort4
    const int ar = tid >> 4, aq = tid & 15;
    const float* gA = X + (size_t)(row0 + ar)*D_ + aq*4;
    // B stage: 2 chunks: idx=tid+it*1024 -> (n=idx>>3, c=idx&7): bf16x8
    const int bn0 = tid >> 3, bc = tid & 7;
    float4 a0 = *(const float4*)gA;
    bf16x8 b0 = *(const bf16x8*)(Wt + (size_t)bn0*512 + bc*8);
    bf16x8 b1 = *(const bf16x8*)(Wt + (size_t)(bn0+128)*512 + bc*8);

    f32x4 acc[4] = {};

    for (int t = 0; t < 8; ++t) {
        __syncthreads();
        {
            ushort4 av = make_ushort4(f2b(a0.x), f2b(a0.y), f2b(a0.z), f2b(a0.w));
            *(ushort4*)&At[ar*64 + (((aq>>1) ^ (ar & 7)) << 3) + ((aq & 1) << 2)] = av;
            *(bf16x8*)&Bt[bn0*64 + ((bc ^ (bn0 & 7)) << 3)] = b0;
            *(bf16x8*)&Bt[(bn0+128)*64 + ((bc ^ ((bn0+128) & 7)) << 3)] = b1;
        }
        __syncthreads();
        if (t < 7) {
            a0 = *(const float4*)(gA + (t+1)*64);
            b0 = *(const bf16x8*)(Wt + (size_t)bn0*512 + (t+1)*64 + bc*8);
            b1 = *(const bf16x8*)(Wt + (size_t)(bn0+128)*512 + (t+1)*64 + bc*8);
        }
        #pragma unroll
        for (int ks = 0; ks < 2; ++ks) {
            bf16x8 af[4], bfr;
            #pragma unroll
            for (int m = 0; m < 4; ++m) {
                int r = m*16 + ln15;
                af[m] = *(const bf16x8*)&At[r*64 + (((ks*4 + ln4) ^ (r & 7)) << 3)];
            }
            {
                int r = wave*16 + ln15;
                bfr = *(const bf16x8*)&Bt[r*64 + (((ks*4 + ln4) ^ (r & 7)) << 3)];
            }
            #pragma unroll
            for (int m = 0; m < 4; ++m)
                acc[m] = __builtin_amdgcn_mfma_f32_16x16x32_bf16(af[m], bfr, acc[m], 0, 0, 0);
        }
    }
    __syncthreads();                         // GEMM reads done; re-carve LDS

    u16* Qb_l = lds;          // [64][64]   swizzled
    u16* Kb_l = lds + 4096;   // [64][64]   swizzled
    u16* Kd_l = lds + 8192;   // [64 h][64 j] decayed K^T, swizzled
    u16* Vt_l = lds + 12288;  // [128 v][64 j] V^T, swizzled

    const int mode = wave >> 2;              // 0:Q(w0-3) 1:K(w4-7) >=2:V
    const int col  = wave*16 + ln15;         // global out col 0..255
    #pragma unroll
    for (int m = 0; m < 4; ++m) {
        const int j0 = m*16 + (ln4 << 2);
        const int cj = j0 >> 3;
        u16 pk[4];
        #pragma unroll
        for (int r = 0; r < 4; ++r) {
            int jrow = j0 + r;
            int pos  = (row0 + jrow) & (L_ - 1);
            float v = acc[m][r];
            float p = __shfl_xor(v, 1, 64);
            if (mode < 2) {
                int h = col & 63;
                float4 tt = T[pos*32 + (h >> 1)];
                float c = (mode == 0) ? tt.x : tt.z;
                float s = (mode == 0) ? tt.y : tt.w;
                float o = ((h & 1) == 0) ? (v*c - p*s) : (v*c + p*s);
                u16 ob = f2b(o);
                int swz = jrow*64 + (((h >> 3) ^ (jrow & 7)) << 3) + (h & 7);
                if (mode == 0) Qb_l[swz] = ob;
                else {
                    Kb_l[swz] = ob;
                    pk[r] = f2b(o * exp2f((float)(63 - jrow) * L2G_));
                }
            } else {
                pk[r] = f2b(v);
            }
        }
        if (mode == 1) {            // Kd_l[h][j0..j0+3]
            int h = col & 63;
            *(ushort4*)&Kd_l[h*64 + ((cj ^ (h & 7)) << 3) + (j0 & 7)] =
                make_ushort4(pk[0], pk[1], pk[2], pk[3]);
        } else if (mode >= 2) {     // Vt_l[v][j0..j0+3]
            int v = col - 128;
            *(ushort4*)&Vt_l[v*64 + ((cj ^ (v & 7)) << 3) + (j0 & 7)] =
                make_ushort4(pk[0], pk[1], pk[2], pk[3]);
        }
    }
    __syncthreads();

    // flush Qb/Kb/Vt (de-swizzle) while P-MFMA runs
    {
        int i = tid >> 4, c4 = tid & 15;
        int swz = i*64 + (((c4 >> 1) ^ (i & 7)) << 3) + ((c4 & 1) << 2);
        *(ushort4*)&Qb[(size_t)(row0 + i)*64 + c4*4] = *(const ushort4*)&Qb_l[swz];
        *(ushort4*)&Kb[(size_t)(row0 + i)*64 + c4*4] = *(const ushort4*)&Kb_l[swz];
        int v = tid >> 3, c = tid & 7;
        *(bf16x8*)&Vt[(size_t)blockIdx.x*8192 + v*64 + c*8] =
            *(const bf16x8*)&Vt_l[v*64 + ((c ^ (v & 7)) << 3)];
    }
    // P^T[v][h] = sum_j Vt[v][j] * Kd[h][j]; wave: vr=w>>1, hc pair=(w&1)*2
    f32x4 accp[2] = {};
    const int vr = wave >> 1, hcb = (wave & 1) * 2;
    #pragma unroll
    for (int ks = 0; ks < 2; ++ks) {
        int rv = vr*16 + ln15;
        bf16x8 av = *(const bf16x8*)&Vt_l[rv*64 + (((ks*4 + ln4) ^ (rv & 7)) << 3)];
        #pragma unroll
        for (int e = 0; e < 2; ++e) {
            int rh = (hcb + e)*16 + ln15;
            bf16x8 bk = *(const bf16x8*)&Kd_l[rh*64 + (((ks*4 + ln4) ^ (rh & 7)) << 3)];
            accp[e] = __builtin_amdgcn_mfma_f32_16x16x32_bf16(av, bk, accp[e], 0, 0, 0);
        }
    }
    __syncthreads();
    u16* Pb_l = lds;          // [128 v][64 h] linear (overwrites Qb_l/Kb_l)
    #pragma unroll
    for (int e = 0; e < 2; ++e)
        #pragma unroll
        for (int r = 0; r < 4; ++r) {
            int v = vr*16 + (ln4 << 2) + r;
            int h = (hcb + e)*16 + ln15;
            Pb_l[v*64 + h] = f2b(accp[e][r]);
        }
    __syncthreads();
    *(bf16x8*)&Pb[(size_t)blockIdx.x*8192 + tid*8] = *(const bf16x8*)&Pb_l[tid*8];
}

// -------------------------------------------------------------------------
// K2: per-chunk output (writes ALL of d_out). 1024 thr, 16 waves.
//   S^T from 16-chunk Pb window (f32 acc) -> bf16 LDS
//   scores = QK^T, decay+mask -> As ; O = gamma^(i+1)*Q@S + As@V^T
// -------------------------------------------------------------------------
#define LDSFRAG(buf, rowblk, ks) \
    (*(const bf16x8*)&(buf)[((rowblk)*16 + ln15)*64 + \
        ((((ks)*4 + ln4) ^ ((((rowblk)*16 + ln15)) & 7)) << 3)])

__global__ __launch_bounds__(1024) void k_chunk(
    const u16* __restrict__ Qb, const u16* __restrict__ Kb,
    const u16* __restrict__ Vt, const u16* __restrict__ Pb,
    float* __restrict__ Out)
{
    __shared__ __align__(16) u16 Qs[4096];    // [i][h]
    __shared__ __align__(16) u16 Ks_[4096];   // [j][h]
    __shared__ __align__(16) u16 Vs[8192];    // [v][j]
    __shared__ __align__(16) u16 Ss[8192];    // [v][h] = S^T
    __shared__ __align__(16) u16 As[4096];    // [i][j] decayed scores

    const int tid  = threadIdx.x;
    const int lane = tid & 63;
    const int ln15 = lane & 15, ln4 = lane >> 4;
    const int wave = tid >> 6;                 // 0..15
    const int blk  = blockIdx.x;
    const int t    = blk & 63;
    const size_t rowBase = (size_t)blk * 64;

    {   // stage Q, K (ushort4) and V^T (bf16x8) into swizzled LDS
        int i = tid >> 4, c4 = tid & 15;
        int swz = i*64 + (((c4 >> 1) ^ (i & 7)) << 3) + ((c4 & 1) << 2);
        *(ushort4*)&Qs[swz]  = *(const ushort4*)&Qb[(rowBase + i)*64 + c4*4];
        *(ushort4*)&Ks_[swz] = *(const ushort4*)&Kb[(rowBase + i)*64 + c4*4];
        int v = tid >> 3, c = tid & 7;
        *(bf16x8*)&Vs[v*64 + ((c ^ (v & 7)) << 3)] =
            *(const bf16x8*)&Vt[(size_t)blk*8192 + v*64 + c*8];
    }
    {   // S^T build: thread owns (v = tid>>3, 8 h at h0=(tid&7)*8)
        int v = tid >> 3, h0 = (tid & 7) * 8;
        float acc[8] = {};
        int nwin = (t < 16) ? t : 16;
        const u16* pb = Pb + (size_t)(blk - 1)*8192 + v*64 + h0;
        float w = 1.0f;
        #pragma unroll 4
        for (int s = 0; s < nwin; ++s) {
            bf16x8 p0 = *(const bf16x8*)(pb - (size_t)s*8192);
            #pragma unroll
            for (int e = 0; e < 8; ++e)
                acc[e] = fmaf(w, b2f((u16)p0[e]), acc[e]);
            w *= GC_;
        }
        bf16x8 s0;
        #pragma unroll
        for (int e = 0; e < 8; ++e) s0[e] = (short)f2b(acc[e]);
        *(bf16x8*)&Ss[v*64 + (((h0 >> 3) ^ (v & 7)) << 3)] = s0;
    }
    __syncthreads();

    const int fr  = wave & 3;            // i-block
    const int fc  = wave >> 2;           // j-block (QK^T)
    const int vcb = (wave >> 2) * 2;     // v-block pair base

    // QK^T: one 16x16 tile per wave
    f32x4 sacc = {};
    #pragma unroll
    for (int ks = 0; ks < 2; ++ks)
        sacc = __builtin_amdgcn_mfma_f32_16x16x32_bf16(
            LDSFRAG(Qs, fr, ks), LDSFRAG(Ks_, fc, ks), sacc, 0, 0, 0);
    #pragma unroll
    for (int r = 0; r < 4; ++r) {
        int i = fr*16 + (ln4 << 2) + r;
        int j = fc*16 + ln15;
        float a = (j <= i) ? sacc[r] * exp2f((float)(i - j) * L2G_) : 0.0f;
        As[i*64 + (((j >> 3) ^ (i & 7)) << 3) + (j & 7)] = f2b(a);
    }
    // cross term: O = Q @ S (scale gamma^(i+1))
    f32x4 oacc[2] = {};
    #pragma unroll
    for (int ks = 0; ks < 2; ++ks) {
        bf16x8 aq = LDSFRAG(Qs, fr, ks);
        #pragma unroll
        for (int n = 0; n < 2; ++n)
            oacc[n] = __builtin_amdgcn_mfma_f32_16x16x32_bf16(aq, LDSFRAG(Ss, vcb+n, ks), oacc[n], 0, 0, 0);
    }
    #pragma unroll
    for (int r = 0; r < 4; ++r) {
        float g = exp2f((float)(fr*16 + (ln4 << 2) + r + 1) * L2G_);
        oacc[0][r] *= g; oacc[1][r] *= g;
    }
    __syncthreads();
    // intra term: O += As @ V^T
    #pragma unroll
    for (int ks = 0; ks < 2; ++ks) {
        bf16x8 aa = LDSFRAG(As, fr, ks);
        #pragma unroll
        for (int n = 0; n < 2; ++n)
            oacc[n] = __builtin_amdgcn_mfma_f32_16x16x32_bf16(aa, LDSFRAG(Vs, vcb+n, ks), oacc[n], 0, 0, 0);
    }
    #pragma unroll
    for (int n = 0; n < 2; ++n)
        #pragma unroll
        for (int r = 0; r < 4; ++r) {
            int i = fr*16 + (ln4 << 2) + r;
            int v = (vcb+n)*16 + ln15;
            Out[(rowBase + i)*VD_ + v] = oacc[n][r];
        }
}

extern "C" void kernel_launch(void* const* d_in, const int* in_sizes, int n_in,
                              void* d_out, int out_size, void* d_ws, size_t ws_size,
                              hipStream_t stream)
{
    const float* X  = (const float*)d_in[0];
    const float* WQ = (const float*)d_in[1];
    const float* WK = (const float*)d_in[2];
    const float* WV = (const float*)d_in[3];
    float* out = (float*)d_out;

    u16* Wt = (u16*)d_ws;                       // 256 KB
    u16* Qb = Wt + 131072;                      // 2 MB
    u16* Kb = Qb + 1048576;                     // 2 MB
    u16* Vt = Kb + 1048576;                     // 4 MB
    u16* Pb = Vt + 2097152;                     // 4 MB
    float4* T = (float4*)(Pb + 2097152);        // 2 MB

    k_prep <<<512, 512,  0, stream>>>(WQ, WK, WV, Wt, T);
    k_projm<<<256, 1024, 0, stream>>>(X, Wt, T, Qb, Kb, Vt, Pb);
    k_chunk<<<256, 1024, 0, stream>>>(Qb, Kb, Vt, Pb, out);
}